// Round 6
// baseline (997.773 us; speedup 1.0000x reference)
//
#include <hip/hip_runtime.h>

typedef __bf16 bf16_t;
typedef __bf16 bf16x4 __attribute__((ext_vector_type(4)));
typedef __bf16 bf16x8 __attribute__((ext_vector_type(8)));
typedef float  f32x4  __attribute__((ext_vector_type(4)));

#define HID    128
#define DIO    80
#define G4     512
#define TSTEP  512
#define BB     16
#define NBATCH 4096
#define NBLK   (NBATCH / BB)
#define HSTR   136  // LDS row stride (bf16 elems)

// Activation-domain scaling folded into the weights (preprocessing):
//   i,f,o rows scaled by -log2(e)  -> exp2(acc) = e^{-gate}
//   g rows scaled by +2*log2(e)    -> exp2(acc) = e^{2g}
// c state kept in the 2*log2(e)-scaled domain so tanh(c) = (exp2(c')-1)/(exp2(c')+1).
#define NL2E  -1.4426950408889634f
#define P2L2E  2.8853900817779268f

// Fragment layout (identical indexing for A- and B-operand of 16x16x32 bf16):
// frag tile (ntile,kt): elem[lane*8+j] = W[n=ntile*16+(lane&15)][k=kt*32+(lane>>4)*8+j]
__device__ bf16_t g_weff_frags[128 * 512];
__device__ bf16_t g_whh_frags[128 * 512];
__device__ bf16_t g_wfc_frags[20 * 512];
__device__ float  g_weff[G4 * HID];
__device__ float  g_beff[G4];
__device__ float  g_b1[G4];

// W_eff = W_hh + W_ih @ W_fc ; b_eff = b_ih + b_hh + W_ih @ b_fc ; b1 = b_ih + b_hh
// All outputs pre-scaled per-row by the activation-domain constants.
__global__ void k_weff(const float* __restrict__ W_ih, const float* __restrict__ W_hh,
                       const float* __restrict__ b_ih, const float* __restrict__ b_hh,
                       const float* __restrict__ W_fc, const float* __restrict__ b_fc) {
  int gid = blockIdx.x * blockDim.x + threadIdx.x;
  int g = gid >> 7, k = gid & 127;
  float sc = ((g >> 7) == 2) ? P2L2E : NL2E;  // gate order i,f,g,o; g-gate rows = [256,384)
  float acc = W_hh[g * HID + k];
#pragma unroll 8
  for (int d = 0; d < DIO; ++d)
    acc = fmaf(W_ih[g * DIO + d], W_fc[d * HID + k], acc);
  g_weff[g * HID + k] = acc * sc;
  if (k == 0) {
    float bb = b_ih[g] + b_hh[g];
    g_b1[g] = bb * sc;
    float be = bb;
    for (int d = 0; d < DIO; ++d) be = fmaf(W_ih[g * DIO + d], b_fc[d], be);
    g_beff[g] = be * sc;
  }
}

__global__ void k_frag(const float* __restrict__ W_hh, const float* __restrict__ W_fc) {
  int tile = blockIdx.x;  // 0..275
  int lane = threadIdx.x;
  int c = lane & 15, q = lane >> 4;
  if (tile < 128) {
    int gtile = tile >> 2, kt = tile & 3;
    int n = gtile * 16 + c;
#pragma unroll
    for (int j = 0; j < 8; ++j)
      g_weff_frags[tile * 512 + lane * 8 + j] = (bf16_t)g_weff[n * HID + kt * 32 + q * 8 + j];
  } else if (tile < 256) {
    int t2 = tile - 128;
    int gtile = t2 >> 2, kt = t2 & 3;
    int n = gtile * 16 + c;
    float sc = ((n >> 7) == 2) ? P2L2E : NL2E;
#pragma unroll
    for (int j = 0; j < 8; ++j)
      g_whh_frags[t2 * 512 + lane * 8 + j] = (bf16_t)(W_hh[n * HID + kt * 32 + q * 8 + j] * sc);
  } else {
    int t2 = tile - 256;  // 0..19 (W_fc unscaled: y output path)
    int yt = t2 >> 2, kt = t2 & 3;
    int n = yt * 16 + c;
#pragma unroll
    for (int j = 0; j < 8; ++j)
      g_wfc_frags[t2 * 512 + lane * 8 + j] = (bf16_t)W_fc[n * HID + kt * 32 + q * 8 + j];
  }
}

__device__ __forceinline__ float fexp2(float x) { return __builtin_amdgcn_exp2f(x); }
__device__ __forceinline__ float frcp(float x)  { return __builtin_amdgcn_rcpf(x); }

#define MFMA16(A, B, C) __builtin_amdgcn_mfma_f32_16x16x32_bf16((A), (B), (C), 0, 0, 0)
#define SGB(m, n) __builtin_amdgcn_sched_group_barrier((m), (n), 0)

// Pointwise tail for one r of one tile (identical DAG to prior rounds -> bit-identical).
#define TAILR(AI, AF, AG, AO, CST, HV, R)                                              \
  do {                                                                                 \
    float Eg = fexp2(AG[R]); /* e^2g */                                                \
    float ag = 1.0f + Eg;                                                              \
    float Ei = fexp2(AI[R]); /* e^-i */                                                \
    float ai = 1.0f + Ei;                                                              \
    float Ef = fexp2(AF[R]); /* e^-f */                                                \
    float af = 1.0f + Ef;                                                              \
    float P1 = ai * ag;                                                                \
    float Rr = frcp(P1 * af);                                                          \
    float tg = __builtin_fmaf(Eg, P2L2E, -P2L2E); /* 2L*(Eg-1) */                      \
    float m2 = tg * af;                                                                \
    float u  = __builtin_fmaf(P1, CST[R], m2);                                         \
    float cn = u * Rr; /* = sig(f)*c + 2L*sig(i)*tanh(g) */                            \
    CST[R] = cn;                                                                       \
    float cc = fminf(cn, 80.0f); /* exp2 overflow guard */                             \
    float Ec = fexp2(cc);        /* e^2c */                                            \
    float Eo = fexp2(AO[R]);     /* e^-o */                                            \
    float R2 = frcp((1.0f + Eo) * (1.0f + Ec));                                        \
    HV[R] = (bf16_t)((Ec - 1.0f) * R2); /* sig(o)*tanh(c) */                           \
  } while (0)

// 256 blocks x 256 threads (4 waves -> 1 wave/SIMD). Block owns 16 batch rows for all 512 steps.
// Each wave owns 32 hidden units = unit-tiles T0=2w, T1=2w+1 (8 chains, 32 MFMAs/step).
// KEY: T1's 16 gate-MFMAs are data-independent of T0's pointwise tail -> interleave them
// {T1-chain-kt , T0-tail-r} in source, pinned with sched_group_barrier, so the matrix pipe
// and the VALU/trans pipe run CONCURRENTLY inside one wave (pipe-sum -> partial pipe-max).
// Every wave carries y-work (w0: dio-tiles 0+4) so post-barrier ds_read latency is always
// filled by register-resident y-MFMAs + store.
__global__ __launch_bounds__(256, 1) void k_lstm(const float* __restrict__ h0,
                                                 const float* __restrict__ b_fc,
                                                 float* __restrict__ out) {
  __shared__ __align__(16) bf16_t hbuf[2][BB * HSTR];
  const int tid = threadIdx.x;
  const int lane = tid & 63;
  const int w = tid >> 6;  // 0..3
  const int c = lane & 15, q = lane >> 4;
  const int b0 = blockIdx.x * BB;

  // stage h0 -> hbuf[0]
  for (int i = tid; i < BB * HID; i += 256) {
    int r = i >> 7, k = i & 127;
    hbuf[0][r * HSTR + k] = (bf16_t)h0[(long)(b0 + r) * HID + k];
  }

  // y-projection A-fragments: wave w owns dio-tile w; wave 0 additionally owns tile 4.
  bf16x8 Wy0[4], Wy4[4];
  f32x4  yb0, yb4;
#pragma unroll
  for (int kt = 0; kt < 4; ++kt)
    Wy0[kt] = *(const bf16x8*)&g_wfc_frags[(w * 4 + kt) * 512 + lane * 8];
#pragma unroll
  for (int r = 0; r < 4; ++r) yb0[r] = b_fc[w * 16 + q * 4 + r];
  if (w == 0) {
#pragma unroll
    for (int kt = 0; kt < 4; ++kt)
      Wy4[kt] = *(const bf16x8*)&g_wfc_frags[(4 * 4 + kt) * 512 + lane * 8];
#pragma unroll
    for (int r = 0; r < 4; ++r) yb4[r] = b_fc[4 * 16 + q * 4 + r];
  }

  bf16x8 Wg[2][4][4];  // [tile][gate][ktile] — 128 VGPRs, register-resident
  f32x4  bias[2][4];
  auto load_wg = [&](const bf16_t* frags, const float* bsrc) {
#pragma unroll
    for (int U = 0; U < 2; ++U)
#pragma unroll
      for (int G = 0; G < 4; ++G) {
        int gtile = G * 8 + (2 * w + U);
#pragma unroll
        for (int r = 0; r < 4; ++r) bias[U][G][r] = bsrc[gtile * 16 + q * 4 + r];
#pragma unroll
        for (int kt = 0; kt < 4; ++kt)
          Wg[U][G][kt] = *(const bf16x8*)&frags[(gtile * 4 + kt) * 512 + lane * 8];
      }
  };

  f32x4 cst0 = (f32x4){0, 0, 0, 0};  // c state (2*log2e-scaled), tile T0
  f32x4 cst1 = (f32x4){0, 0, 0, 0};  // tile T1
  bf16x8 hfA[4], hfB[4];             // ping-pong B-fragments of h (h^T)

  __syncthreads();
#pragma unroll
  for (int kt = 0; kt < 4; ++kt)
    hfA[kt] = *(const bf16x8*)&hbuf[0][c * HSTR + kt * 32 + q * 8];

  float* outp0 = out + (long)(b0 + c) * TSTEP * DIO + w * 16 + q * 4;  // dio-tile w, row 0
  float* outp4 = out + (long)(b0 + c) * TSTEP * DIO + 64 + q * 4;      // dio-tile 4 (w0 only)

// One recurrence iteration. CUR holds h(t-1) frags; writes h(t) to hbuf[BUF]; post-barrier:
// ds_read h(t) -> NXT, then y(h(t-1)) from CUR (register-resident -> fills read latency).
// Gate chains kt-outer (4-way MFMA ILP); T1 chains interleaved with T0 tail.
#define ITER(CUR, NXT, BUF, EMIT)                                                      \
  do {                                                                                 \
    f32x4 aI0, aF0, aG0, aO0, aI1, aF1, aG1, aO1;                                      \
    bf16x4 hv0, hv1;                                                                   \
    /* T0 chains: kt-outer, 4 independent gate streams */                              \
    aI0 = MFMA16(Wg[0][0][0], CUR[0], bias[0][0]);                                     \
    aF0 = MFMA16(Wg[0][1][0], CUR[0], bias[0][1]);                                     \
    aG0 = MFMA16(Wg[0][2][0], CUR[0], bias[0][2]);                                     \
    aO0 = MFMA16(Wg[0][3][0], CUR[0], bias[0][3]);                                     \
    aI0 = MFMA16(Wg[0][0][1], CUR[1], aI0);                                            \
    aF0 = MFMA16(Wg[0][1][1], CUR[1], aF0);                                            \
    aG0 = MFMA16(Wg[0][2][1], CUR[1], aG0);                                            \
    aO0 = MFMA16(Wg[0][3][1], CUR[1], aO0);                                            \
    aI0 = MFMA16(Wg[0][0][2], CUR[2], aI0);                                            \
    aF0 = MFMA16(Wg[0][1][2], CUR[2], aF0);                                            \
    aG0 = MFMA16(Wg[0][2][2], CUR[2], aG0);                                            \
    aO0 = MFMA16(Wg[0][3][2], CUR[2], aO0);                                            \
    aI0 = MFMA16(Wg[0][0][3], CUR[3], aI0);                                            \
    aF0 = MFMA16(Wg[0][1][3], CUR[3], aF0);                                            \
    aG0 = MFMA16(Wg[0][2][3], CUR[3], aG0);                                            \
    aO0 = MFMA16(Wg[0][3][3], CUR[3], aO0);                                            \
    /* T1 chains interleaved with T0 tail: each {4 MFMA, 1 tail-r} pair independent */ \
    aI1 = MFMA16(Wg[1][0][0], CUR[0], bias[1][0]);                                     \
    aF1 = MFMA16(Wg[1][1][0], CUR[0], bias[1][1]);                                     \
    aG1 = MFMA16(Wg[1][2][0], CUR[0], bias[1][2]);                                     \
    aO1 = MFMA16(Wg[1][3][0], CUR[0], bias[1][3]);                                     \
    TAILR(aI0, aF0, aG0, aO0, cst0, hv0, 0);                                           \
    aI1 = MFMA16(Wg[1][0][1], CUR[1], aI1);                                            \
    aF1 = MFMA16(Wg[1][1][1], CUR[1], aF1);                                            \
    aG1 = MFMA16(Wg[1][2][1], CUR[1], aG1);                                            \
    aO1 = MFMA16(Wg[1][3][1], CUR[1], aO1);                                            \
    TAILR(aI0, aF0, aG0, aO0, cst0, hv0, 1);                                           \
    aI1 = MFMA16(Wg[1][0][2], CUR[2], aI1);                                            \
    aF1 = MFMA16(Wg[1][1][2], CUR[2], aF1);                                            \
    aG1 = MFMA16(Wg[1][2][2], CUR[2], aG1);                                            \
    aO1 = MFMA16(Wg[1][3][2], CUR[2], aO1);                                            \
    TAILR(aI0, aF0, aG0, aO0, cst0, hv0, 2);                                           \
    aI1 = MFMA16(Wg[1][0][3], CUR[3], aI1);                                            \
    aF1 = MFMA16(Wg[1][1][3], CUR[3], aF1);                                            \
    aG1 = MFMA16(Wg[1][2][3], CUR[3], aG1);                                            \
    aO1 = MFMA16(Wg[1][3][3], CUR[3], aO1);                                            \
    TAILR(aI0, aF0, aG0, aO0, cst0, hv0, 3);                                           \
    /* T1 tail */                                                                      \
    TAILR(aI1, aF1, aG1, aO1, cst1, hv1, 0);                                           \
    TAILR(aI1, aF1, aG1, aO1, cst1, hv1, 1);                                           \
    TAILR(aI1, aF1, aG1, aO1, cst1, hv1, 2);                                           \
    TAILR(aI1, aF1, aG1, aO1, cst1, hv1, 3);                                           \
    *(bf16x4*)&hbuf[BUF][c * HSTR + (2 * w) * 16 + q * 4]     = hv0;                   \
    *(bf16x4*)&hbuf[BUF][c * HSTR + (2 * w + 1) * 16 + q * 4] = hv1;                   \
    /* pin: T0 MFMA block, then {MFMA4 | VALU-tail}x4 interleave, tail rest, writes */ \
    SGB(0x008, 16);                                                                    \
    SGB(0x008, 4); SGB(0x002, 24);                                                     \
    SGB(0x008, 4); SGB(0x002, 24);                                                     \
    SGB(0x008, 4); SGB(0x002, 24);                                                     \
    SGB(0x008, 4); SGB(0x002, 24);                                                     \
    SGB(0x002, 96);                                                                    \
    SGB(0x200, 2);                                                                     \
    __syncthreads();                                                                   \
    _Pragma("unroll")                                                                  \
    for (int kt = 0; kt < 4; ++kt)                                                     \
      NXT[kt] = *(const bf16x8*)&hbuf[BUF][c * HSTR + kt * 32 + q * 8];                \
    if (EMIT) { /* y(h(t-1)) from CUR: register-resident, fills ds_read latency */     \
      f32x4 ya = MFMA16(Wy0[0], CUR[0], yb0);                                          \
      ya = MFMA16(Wy0[1], CUR[1], ya);                                                 \
      ya = MFMA16(Wy0[2], CUR[2], ya);                                                 \
      ya = MFMA16(Wy0[3], CUR[3], ya);                                                 \
      *(f32x4*)outp0 = ya;                                                             \
      outp0 += DIO;                                                                    \
      if (w == 0) {                                                                    \
        f32x4 yc = MFMA16(Wy4[0], CUR[0], yb4);                                        \
        yc = MFMA16(Wy4[1], CUR[1], yc);                                               \
        yc = MFMA16(Wy4[2], CUR[2], yc);                                               \
        yc = MFMA16(Wy4[3], CUR[3], yc);                                               \
        *(f32x4*)outp4 = yc;                                                           \
        outp4 += DIO;                                                                  \
      }                                                                                \
    }                                                                                  \
  } while (0)

  // iter 1: x0 == 0 => gates = h0 @ W_hh^T + (b_ih + b_hh); no y emitted yet
  load_wg(g_whh_frags, g_b1);
  ITER(hfA, hfB, 1, false);
  // iters 2..512: fused recurrence (x eliminated: W_eff = W_hh + W_ih@W_fc)
  load_wg(g_weff_frags, g_beff);
  for (int p = 0; p < 255; ++p) {
    ITER(hfB, hfA, 0, true);
    ITER(hfA, hfB, 1, true);
  }
  ITER(hfB, hfA, 0, true);  // iter 512: emits y(h511), loads h512 -> hfA

  // epilogue: y(h512) -> row 511
  {
    f32x4 ya = MFMA16(Wy0[0], hfA[0], yb0);
    ya = MFMA16(Wy0[1], hfA[1], ya);
    ya = MFMA16(Wy0[2], hfA[2], ya);
    ya = MFMA16(Wy0[3], hfA[3], ya);
    *(f32x4*)outp0 = ya;
    if (w == 0) {
      f32x4 yc = MFMA16(Wy4[0], hfA[0], yb4);
      yc = MFMA16(Wy4[1], hfA[1], yc);
      yc = MFMA16(Wy4[2], hfA[2], yc);
      yc = MFMA16(Wy4[3], hfA[3], yc);
      *(f32x4*)outp4 = yc;
    }
  }
#undef ITER
}

extern "C" void kernel_launch(void* const* d_in, const int* in_sizes, int n_in,
                              void* d_out, int out_size, void* d_ws, size_t ws_size,
                              hipStream_t stream) {
  const float* h0   = (const float*)d_in[0];
  const float* W_ih = (const float*)d_in[1];
  const float* W_hh = (const float*)d_in[2];
  const float* b_ih = (const float*)d_in[3];
  const float* b_hh = (const float*)d_in[4];
  const float* W_fc = (const float*)d_in[5];
  const float* b_fc = (const float*)d_in[6];
  float* out = (float*)d_out;

  k_weff<<<256, 256, 0, stream>>>(W_ih, W_hh, b_ih, b_hh, W_fc, b_fc);
  k_frag<<<276, 64, 0, stream>>>(W_hh, W_fc);
  k_lstm<<<NBLK, 256, 0, stream>>>(h0, b_fc, out);
}

// Round 7
// 962.729 us; speedup vs baseline: 1.0364x; 1.0364x over previous
//
#include <hip/hip_runtime.h>

typedef __bf16 bf16_t;
typedef __bf16 bf16x4 __attribute__((ext_vector_type(4)));
typedef __bf16 bf16x8 __attribute__((ext_vector_type(8)));
typedef float  f32x4  __attribute__((ext_vector_type(4)));

#define HID    128
#define DIO    80
#define G4     512
#define TSTEP  512
#define BB     16
#define NBATCH 4096
#define NBLK   (NBATCH / BB)
#define HSTR   136  // LDS row stride (bf16 elems)

// Activation-domain scaling folded into the weights (preprocessing):
//   i,f,o rows scaled by -log2(e)  -> exp2(acc) = e^{-gate}
//   g rows scaled by +2*log2(e)    -> exp2(acc) = e^{2g}
// c state kept in the 2*log2(e)-scaled domain so tanh(c) = (exp2(c')-1)/(exp2(c')+1).
#define NL2E  -1.4426950408889634f
#define P2L2E  2.8853900817779268f

// Fragment layout (identical indexing for A- and B-operand of 16x16x32 bf16):
// frag tile (ntile,kt): elem[lane*8+j] = W[n=ntile*16+(lane&15)][k=kt*32+(lane>>4)*8+j]
__device__ bf16_t g_weff_frags[128 * 512];
__device__ bf16_t g_whh_frags[128 * 512];
__device__ bf16_t g_wfc_frags[20 * 512];
__device__ float  g_weff[G4 * HID];
__device__ float  g_beff[G4];
__device__ float  g_b1[G4];

// W_eff = W_hh + W_ih @ W_fc ; b_eff = b_ih + b_hh + W_ih @ b_fc ; b1 = b_ih + b_hh
__global__ void k_weff(const float* __restrict__ W_ih, const float* __restrict__ W_hh,
                       const float* __restrict__ b_ih, const float* __restrict__ b_hh,
                       const float* __restrict__ W_fc, const float* __restrict__ b_fc) {
  int gid = blockIdx.x * blockDim.x + threadIdx.x;
  int g = gid >> 7, k = gid & 127;
  float sc = ((g >> 7) == 2) ? P2L2E : NL2E;  // gate order i,f,g,o; g-gate rows = [256,384)
  float acc = W_hh[g * HID + k];
#pragma unroll 8
  for (int d = 0; d < DIO; ++d)
    acc = fmaf(W_ih[g * DIO + d], W_fc[d * HID + k], acc);
  g_weff[g * HID + k] = acc * sc;
  if (k == 0) {
    float bb = b_ih[g] + b_hh[g];
    g_b1[g] = bb * sc;
    float be = bb;
    for (int d = 0; d < DIO; ++d) be = fmaf(W_ih[g * DIO + d], b_fc[d], be);
    g_beff[g] = be * sc;
  }
}

__global__ void k_frag(const float* __restrict__ W_hh, const float* __restrict__ W_fc) {
  int tile = blockIdx.x;  // 0..275
  int lane = threadIdx.x;
  int c = lane & 15, q = lane >> 4;
  if (tile < 128) {
    int gtile = tile >> 2, kt = tile & 3;
    int n = gtile * 16 + c;
#pragma unroll
    for (int j = 0; j < 8; ++j)
      g_weff_frags[tile * 512 + lane * 8 + j] = (bf16_t)g_weff[n * HID + kt * 32 + q * 8 + j];
  } else if (tile < 256) {
    int t2 = tile - 128;
    int gtile = t2 >> 2, kt = t2 & 3;
    int n = gtile * 16 + c;
    float sc = ((n >> 7) == 2) ? P2L2E : NL2E;
#pragma unroll
    for (int j = 0; j < 8; ++j)
      g_whh_frags[t2 * 512 + lane * 8 + j] = (bf16_t)(W_hh[n * HID + kt * 32 + q * 8 + j] * sc);
  } else {
    int t2 = tile - 256;  // 0..19 (W_fc unscaled: y output path)
    int yt = t2 >> 2, kt = t2 & 3;
    int n = yt * 16 + c;
#pragma unroll
    for (int j = 0; j < 8; ++j)
      g_wfc_frags[t2 * 512 + lane * 8 + j] = (bf16_t)W_fc[n * HID + kt * 32 + q * 8 + j];
  }
}

__device__ __forceinline__ float fexp2(float x) { return __builtin_amdgcn_exp2f(x); }
__device__ __forceinline__ float frcp(float x)  { return __builtin_amdgcn_rcpf(x); }

#define MFMA16(A, B, C) __builtin_amdgcn_mfma_f32_16x16x32_bf16((A), (B), (C), 0, 0, 0)

// Pointwise tail for one r (identical DAG to prior rounds -> bit-identical results).
#define TAILR(ACC, CST, HV, R)                                                         \
  do {                                                                                 \
    float Eg = fexp2(ACC[2][R]); /* e^2g */                                            \
    float ag = 1.0f + Eg;                                                              \
    float Ei = fexp2(ACC[0][R]); /* e^-i */                                            \
    float ai = 1.0f + Ei;                                                              \
    float Ef = fexp2(ACC[1][R]); /* e^-f */                                            \
    float af = 1.0f + Ef;                                                              \
    float P1 = ai * ag;                                                                \
    float Rr = frcp(P1 * af);                                                          \
    float tg = __builtin_fmaf(Eg, P2L2E, -P2L2E); /* 2L*(Eg-1) */                      \
    float m2 = tg * af;                                                                \
    float u  = __builtin_fmaf(P1, CST[R], m2);                                         \
    float cn = u * Rr; /* = sig(f)*c + 2L*sig(i)*tanh(g) */                            \
    CST[R] = cn;                                                                       \
    float cc = fminf(cn, 80.0f); /* exp2 overflow guard */                             \
    float Ec = fexp2(cc);        /* e^2c */                                            \
    float Eo = fexp2(ACC[3][R]); /* e^-o */                                            \
    float R2 = frcp((1.0f + Eo) * (1.0f + Ec));                                        \
    HV[R] = (bf16_t)((Ec - 1.0f) * R2); /* sig(o)*tanh(c) */                           \
  } while (0)

// 256 blocks x 512 threads (8 waves, 2/SIMD). Block owns 16 batch rows for 512 steps.
// SPLIT-H PIPELINE: waves 0-3 (LOW) own units 0-63, waves 4-7 (HIGH) own 64-127; SIMD s
// hosts waves s (LOW) and s+4 (HIGH). Gates split by k: kt01 needs only h_low, kt23 only
// h_high. Two barriers per step:
//   S1(t) [h_low(t) visible]:  all read kt01 + build acc(t+1) kt01; HIGH runs tail(t)
//         (register-only VALU/trans -> overlaps everyone's MFMAs) + writes h_high(t).
//   S2(t) [h_high(t) visible]: all read kt23 + finish acc(t+1); w<5 emit y(h(t-1))
//         (register CUR -> fills read window); LOW runs tail(t+1) + writes h_low(t+1).
// Every interval: one tail-ing wave (trans pipe) + ~16 MFMAs (matrix pipe) per SIMD ->
// genuine dual-pipe overlap with inter-wave latency cover. Scoped setprio on the tail
// wave (role-split exists -> T5 regime). Dataflow/accumulation order bit-identical to r3.
__global__ __launch_bounds__(512, 2) void k_lstm(const float* __restrict__ h0,
                                                 const float* __restrict__ b_fc,
                                                 float* __restrict__ out) {
  __shared__ __align__(16) bf16_t hbuf[2][BB * HSTR];
  const int tid = threadIdx.x;
  const int lane = tid & 63;
  const int w = tid >> 6;  // 0..7
  const int c = lane & 15, q = lane >> 4;
  const int b0 = blockIdx.x * BB;
  const bool isHigh = (w >= 4);

  // stage h0 -> hbuf[0]
  for (int i = tid; i < BB * HID; i += 512) {
    int r = i >> 7, k = i & 127;
    hbuf[0][r * HSTR + k] = (bf16_t)h0[(long)(b0 + r) * HID + k];
  }

  // W_fc A-fragments: waves 0..4 own y-tile w (dio cols w*16..w*16+16)
  bf16x8 Wy[4];
  f32x4  ybias;
  if (w < 5) {
#pragma unroll
    for (int kt = 0; kt < 4; ++kt)
      Wy[kt] = *(const bf16x8*)&g_wfc_frags[(w * 4 + kt) * 512 + lane * 8];
#pragma unroll
    for (int r = 0; r < 4; ++r) ybias[r] = b_fc[w * 16 + q * 4 + r];
  }

  bf16x8 Wg[4][4];  // [gate][ktile] — register-resident; wave w owns unit-tile w
  f32x4  bias[4];
  auto load_wg = [&](const bf16_t* frags, const float* bsrc) {
#pragma unroll
    for (int G = 0; G < 4; ++G) {
      int gtile = G * 8 + w;
#pragma unroll
      for (int r = 0; r < 4; ++r) bias[G][r] = bsrc[gtile * 16 + q * 4 + r];
#pragma unroll
      for (int kt = 0; kt < 4; ++kt)
        Wg[G][kt] = *(const bf16x8*)&frags[(gtile * 4 + kt) * 512 + lane * 8];
    }
  };

  f32x4 cst = (f32x4){0, 0, 0, 0};   // c state (2*log2e-scaled), batch row c
  bf16x8 hfA[4], hfB[4];             // ping-pong B-fragments of h
  f32x4 accA[4], accB[4];            // double-buffered gate accumulators (HIGH spans a barrier)

  __syncthreads();

  // ---------- step 1 (unpipelined; x0==0 => gates = h0 @ W_hh^T + b1) ----------
#pragma unroll
  for (int kt = 0; kt < 4; ++kt)
    hfA[kt] = *(const bf16x8*)&hbuf[0][c * HSTR + kt * 32 + q * 8];
  load_wg(g_whh_frags, g_b1);
#pragma unroll
  for (int G = 0; G < 4; ++G) accB[G] = MFMA16(Wg[G][0], hfA[0], bias[G]);
#pragma unroll
  for (int kt = 1; kt < 4; ++kt)
#pragma unroll
    for (int G = 0; G < 4; ++G) accB[G] = MFMA16(Wg[G][kt], hfA[kt], accB[G]);
  {
    bf16x4 hv;
    TAILR(accB, cst, hv, 0); TAILR(accB, cst, hv, 1);
    TAILR(accB, cst, hv, 2); TAILR(accB, cst, hv, 3);
    *(bf16x4*)&hbuf[1][c * HSTR + w * 16 + q * 4] = hv;  // h(1), all waves
  }
  __syncthreads();

  load_wg(g_weff_frags, g_beff);
  float* outp = out + (long)(b0 + c) * TSTEP * DIO + w * 16 + q * 4;  // row 0

  // ---------- prologue (t=1 intervals; h(1) fully visible, no HIGH tail, no y) ----------
  hfB[0] = *(const bf16x8*)&hbuf[1][c * HSTR + 0 * 32 + q * 8];
  hfB[1] = *(const bf16x8*)&hbuf[1][c * HSTR + 1 * 32 + q * 8];
#pragma unroll
  for (int G = 0; G < 4; ++G) accA[G] = MFMA16(Wg[G][0], hfB[0], bias[G]);
#pragma unroll
  for (int G = 0; G < 4; ++G) accA[G] = MFMA16(Wg[G][1], hfB[1], accA[G]);
  hfB[2] = *(const bf16x8*)&hbuf[1][c * HSTR + 2 * 32 + q * 8];
  hfB[3] = *(const bf16x8*)&hbuf[1][c * HSTR + 3 * 32 + q * 8];
#pragma unroll
  for (int G = 0; G < 4; ++G) accA[G] = MFMA16(Wg[G][2], hfB[2], accA[G]);
#pragma unroll
  for (int G = 0; G < 4; ++G) accA[G] = MFMA16(Wg[G][3], hfB[3], accA[G]);
  if (!isHigh) {  // tail(2) low half -> h_low(2) into hbuf[0]
    bf16x4 hv;
    TAILR(accA, cst, hv, 0); TAILR(accA, cst, hv, 1);
    TAILR(accA, cst, hv, 2); TAILR(accA, cst, hv, 3);
    *(bf16x4*)&hbuf[0][c * HSTR + w * 16 + q * 4] = hv;
  }
  __syncthreads();  // BAR_L(2)

// One pipelined step t. NXT <- h(t) frags; CUR = h(t-1) (for y). ACCB = acc(t+1) build;
// ACCE = acc(t) (HIGH eats in S1). B0 = t&1 (buffer of h(t)), B1 = (t+1)&1.
#define STEP(NXT, CUR, ACCB, ACCE, B0, B1)                                             \
  do {                                                                                 \
    /* ---- S1(t): h_low(t) visible ---- */                                            \
    NXT[0] = *(const bf16x8*)&hbuf[B0][c * HSTR + 0 * 32 + q * 8];                     \
    NXT[1] = *(const bf16x8*)&hbuf[B0][c * HSTR + 1 * 32 + q * 8];                     \
    if (isHigh) { /* tail(t): register-only, fills the ds_read window */               \
      __builtin_amdgcn_s_setprio(1);                                                   \
      bf16x4 hv;                                                                       \
      TAILR(ACCE, cst, hv, 0); TAILR(ACCE, cst, hv, 1);                                \
      TAILR(ACCE, cst, hv, 2); TAILR(ACCE, cst, hv, 3);                                \
      *(bf16x4*)&hbuf[B0][c * HSTR + w * 16 + q * 4] = hv; /* h_high(t) */             \
      __builtin_amdgcn_s_setprio(0);                                                   \
    }                                                                                  \
    _Pragma("unroll")                                                                  \
    for (int G = 0; G < 4; ++G) ACCB[G] = MFMA16(Wg[G][0], NXT[0], bias[G]);           \
    _Pragma("unroll")                                                                  \
    for (int G = 0; G < 4; ++G) ACCB[G] = MFMA16(Wg[G][1], NXT[1], ACCB[G]);           \
    __syncthreads(); /* BAR_H(t) */                                                    \
    /* ---- S2(t): h_high(t) visible ---- */                                           \
    NXT[2] = *(const bf16x8*)&hbuf[B0][c * HSTR + 2 * 32 + q * 8];                     \
    NXT[3] = *(const bf16x8*)&hbuf[B0][c * HSTR + 3 * 32 + q * 8];                     \
    if (w < 5) { /* y(h(t-1)) from CUR regs: fills the ds_read window */               \
      f32x4 ya = MFMA16(Wy[0], CUR[0], ybias);                                         \
      ya = MFMA16(Wy[1], CUR[1], ya);                                                  \
      ya = MFMA16(Wy[2], CUR[2], ya);                                                  \
      ya = MFMA16(Wy[3], CUR[3], ya);                                                  \
      *(f32x4*)outp = ya;                                                              \
      outp += DIO;                                                                     \
    }                                                                                  \
    _Pragma("unroll")                                                                  \
    for (int G = 0; G < 4; ++G) ACCB[G] = MFMA16(Wg[G][2], NXT[2], ACCB[G]);           \
    _Pragma("unroll")                                                                  \
    for (int G = 0; G < 4; ++G) ACCB[G] = MFMA16(Wg[G][3], NXT[3], ACCB[G]);           \
    if (!isHigh) { /* tail(t+1): acc just completed */                                 \
      __builtin_amdgcn_s_setprio(1);                                                   \
      bf16x4 hv;                                                                       \
      TAILR(ACCB, cst, hv, 0); TAILR(ACCB, cst, hv, 1);                                \
      TAILR(ACCB, cst, hv, 2); TAILR(ACCB, cst, hv, 3);                                \
      *(bf16x4*)&hbuf[B1][c * HSTR + w * 16 + q * 4] = hv; /* h_low(t+1) */            \
      __builtin_amdgcn_s_setprio(0);                                                   \
    }                                                                                  \
    __syncthreads(); /* BAR_L(t+1) */                                                  \
  } while (0)

  // steady state t=2..511 (255 pairs)
  for (int p = 0; p < 255; ++p) {
    STEP(hfA, hfB, accB, accA, 0, 1);  // t even
    STEP(hfB, hfA, accA, accB, 1, 0);  // t odd
  }

  // ---------- epilogue (t=512): HIGH tail(512); then y(h511), y(h512) ----------
  hfA[0] = *(const bf16x8*)&hbuf[0][c * HSTR + 0 * 32 + q * 8];
  hfA[1] = *(const bf16x8*)&hbuf[0][c * HSTR + 1 * 32 + q * 8];
  if (isHigh) {  // tail(512) -> h_high(512)
    bf16x4 hv;
    TAILR(accA, cst, hv, 0); TAILR(accA, cst, hv, 1);
    TAILR(accA, cst, hv, 2); TAILR(accA, cst, hv, 3);
    *(bf16x4*)&hbuf[0][c * HSTR + w * 16 + q * 4] = hv;
  }
  __syncthreads();
  hfA[2] = *(const bf16x8*)&hbuf[0][c * HSTR + 2 * 32 + q * 8];
  hfA[3] = *(const bf16x8*)&hbuf[0][c * HSTR + 3 * 32 + q * 8];
  if (w < 5) {
    f32x4 ya = MFMA16(Wy[0], hfB[0], ybias);  // y(h(511)) -> row 510
    ya = MFMA16(Wy[1], hfB[1], ya);
    ya = MFMA16(Wy[2], hfB[2], ya);
    ya = MFMA16(Wy[3], hfB[3], ya);
    *(f32x4*)outp = ya;
    outp += DIO;
    f32x4 yb = MFMA16(Wy[0], hfA[0], ybias);  // y(h(512)) -> row 511
    yb = MFMA16(Wy[1], hfA[1], yb);
    yb = MFMA16(Wy[2], hfA[2], yb);
    yb = MFMA16(Wy[3], hfA[3], yb);
    *(f32x4*)outp = yb;
  }
#undef STEP
}

extern "C" void kernel_launch(void* const* d_in, const int* in_sizes, int n_in,
                              void* d_out, int out_size, void* d_ws, size_t ws_size,
                              hipStream_t stream) {
  const float* h0   = (const float*)d_in[0];
  const float* W_ih = (const float*)d_in[1];
  const float* W_hh = (const float*)d_in[2];
  const float* b_ih = (const float*)d_in[3];
  const float* b_hh = (const float*)d_in[4];
  const float* W_fc = (const float*)d_in[5];
  const float* b_fc = (const float*)d_in[6];
  float* out = (float*)d_out;

  k_weff<<<256, 256, 0, stream>>>(W_ih, W_hh, b_ih, b_hh, W_fc, b_fc);
  k_frag<<<276, 64, 0, stream>>>(W_hh, W_fc);
  k_lstm<<<NBLK, 512, 0, stream>>>(h0, b_fc, out);
}